// Round 18
// baseline (125.711 us; speedup 1.0000x reference)
//
#include <hip/hip_runtime.h>
#include <hip/hip_bf16.h>

typedef unsigned int u32;
typedef unsigned short u16;
typedef float f32x2 __attribute__((ext_vector_type(2)));
typedef float f32x4 __attribute__((ext_vector_type(4)));
using bf16x8 = __attribute__((ext_vector_type(8))) short;   // MFMA A/B frag (4 VGPRs)
using f32x4v = __attribute__((ext_vector_type(4))) float;   // MFMA C/D frag

#define DEVINL __device__ __forceinline__

// Problem constants: B=8, C=64, D=128, H=128, W=128
// d-split: each tile handles 64 channels (e = 0 or 1). tile id: ((b*128)+p)*2+e.
constexpr int SCAN_LDS = 32768;        // bufA(16K) + bufB(16K)
constexpr int XS = 132;                // k_final transpose staging stride (u16)
constexpr int LDS_X = 128 * XS * 2;    // 33792

DEVINL float bf2f(u16 u) { union { u32 i; float f; } v; v.i = ((u32)u) << 16; return v.f; }
DEVINL float bf2f_lo(u32 u) { union { u32 i; float f; } v; v.i = u << 16; return v.f; }
DEVINL float bf2f_hi(u32 u) { union { u32 i; float f; } v; v.i = u & 0xffff0000u; return v.f; }
DEVINL u16 f2bf(float f) {
  __hip_bfloat16 h = __float2bfloat16(f);
  u16 r; __builtin_memcpy(&r, &h, 2); return r;
}
DEVINL u32 pack2(float a, float b) { return (u32)f2bf(a) | ((u32)f2bf(b) << 16); }

// lgkm-only barrier: LDS visibility + thread sync WITHOUT draining global loads/stores.
DEVINL void barrier_lgkm() {
  asm volatile("s_waitcnt lgkmcnt(0)" ::: "memory");
  __builtin_amdgcn_s_barrier();
  __builtin_amdgcn_sched_barrier(0);
}

// ---------------- P0: A=tanh(A_param), Mrow[dir][c][d] bf16, beff, Wi_bf ----------------
__global__ __launch_bounds__(256) void k_pre(
    const float* __restrict__ Wf, const float* __restrict__ Wo,
    const float* __restrict__ bf_, const float* __restrict__ bo,
    const float* __restrict__ A_param, const float* __restrict__ Wi,
    float* __restrict__ A_t, float* __restrict__ beff,
    u16* __restrict__ Mrow, u16* __restrict__ Wi_bf) {
  const int wg = blockIdx.x, t = threadIdx.x;
  if (wg < 128) {
    const int idx = wg * 256 + t;          // 0..32767
    const int cout = idx >> 9;             // 0..63
    const int k = idx & 511;               // dir*128 + d
    float s = 0.f;
    for (int d = 0; d < 128; ++d) s = fmaf(Wo[cout * 128 + d], Wf[d * 512 + k], s);
    const int dir = k >> 7, dm = k & 127;
    Mrow[(dir * 64 + cout) * 128 + dm] = f2bf(s);
  } else if (wg == 128) {
    if (t < 128) A_t[t] = tanhf(A_param[t]);
    if (t < 64) {
      float s = bo[t];
      for (int d = 0; d < 128; ++d) s = fmaf(Wo[t * 128 + d], bf_[d], s);
      beff[t] = s;
    }
  } else {
#pragma unroll
    for (int k = 0; k < 32; ++k) {
      const int i = t + k * 256;
      Wi_bf[i] = f2bf(Wi[i]);
    }
  }
}

extern __shared__ char smem[];

// ---- Chunked scan (4 chunks x 32), prescaled input (B*x): h = A*h + xv. ----
template <bool REV>
DEVINL void scan_local(char* buf, int dp, int chunk, f32x2 A2) {
  f32x2 h = { 0.f, 0.f };
  const u32 cb = (u32)(dp * 4);
  const int s = chunk * 32;
  u32 nx[8];
#pragma unroll
  for (int j = 0; j < 8; ++j) {
    const int i = REV ? (127 - (s + j)) : (s + j);
    nx[j] = *(const u32*)(buf + i * 128 + (cb ^ ((u32)((i & 7) << 4))));
  }
  for (int ib = 0; ib < 32; ib += 8) {
    u32 cur[8];
#pragma unroll
    for (int j = 0; j < 8; ++j) cur[j] = nx[j];
    if (ib + 8 < 32) {
#pragma unroll
      for (int j = 0; j < 8; ++j) {
        const int i2 = s + ib + 8 + j;
        const int i = REV ? (127 - i2) : i2;
        nx[j] = *(const u32*)(buf + i * 128 + (cb ^ ((u32)((i & 7) << 4))));
      }
    }
#pragma unroll
    for (int j = 0; j < 8; ++j) {
      const int i2 = s + ib + j;
      const int i = REV ? (127 - i2) : i2;
      const f32x2 xv = { bf2f_lo(cur[j]), bf2f_hi(cur[j]) };
      h = A2 * h + xv;
      *(u32*)(buf + i * 128 + (cb ^ ((u32)((i & 7) << 4)))) = pack2(h.x, h.y);
    }
  }
}

// ---- Carry correction: h_i = l_i + A^{j+1} * C. ----
template <bool REV>
DEVINL void scan_fix(char* buf, int dp, int chunk, f32x2 A2) {
  if (chunk == 0) return;
  f32x2 q = A2;
#pragma unroll
  for (int k = 0; k < 5; ++k) q *= q;            // A^32
  const u32 cb = (u32)(dp * 4);
  f32x2 C = { 0.f, 0.f };
  for (int k = 0; k < chunk; ++k) {
    const int i2 = k * 32 + 31;
    const int i = REV ? (127 - i2) : i2;
    const u32 v = *(const u32*)(buf + i * 128 + (cb ^ ((u32)((i & 7) << 4))));
    const f32x2 xv = { bf2f_lo(v), bf2f_hi(v) };
    C = C * q + xv;
  }
  f32x2 p = A2;
  const int s = chunk * 32;
  u32 nx[8];
#pragma unroll
  for (int j = 0; j < 8; ++j) {
    const int i = REV ? (127 - (s + j)) : (s + j);
    nx[j] = *(const u32*)(buf + i * 128 + (cb ^ ((u32)((i & 7) << 4))));
  }
  for (int ib = 0; ib < 32; ib += 8) {
    u32 cur[8];
#pragma unroll
    for (int j = 0; j < 8; ++j) cur[j] = nx[j];
    if (ib + 8 < 32) {
#pragma unroll
      for (int j = 0; j < 8; ++j) {
        const int i2 = s + ib + 8 + j;
        const int i = REV ? (127 - i2) : i2;
        nx[j] = *(const u32*)(buf + i * 128 + (cb ^ ((u32)((i & 7) << 4))));
      }
    }
#pragma unroll
    for (int j = 0; j < 8; ++j) {
      const int i2 = s + ib + j;
      const int i = REV ? (127 - i2) : i2;
      const f32x2 xv = { bf2f_lo(cur[j]), bf2f_hi(cur[j]) };
      const f32x2 hv = p * C + xv;
      *(u32*)(buf + i * 128 + (cb ^ ((u32)((i & 7) << 4)))) = pack2(hv.x, hv.y);
      p *= A2;
    }
  }
}

// Both scans: dir0 = fwd on bufA, dir1 = rev on bufB; 4 chunks each; 256 threads.
DEVINL void run_scans(char* bufA, char* bufB, int t, int e, const float* __restrict__ A_t) {
  const int dp = t & 31, chunk = (t >> 5) & 3, dir = t >> 7;
  const f32x2 a = *(const f32x2*)(A_t + e * 64 + dp * 2);
  char* sb = dir ? bufB : bufA;
  if (dir == 0) scan_local<false>(sb, dp, chunk, a);
  else          scan_local<true >(sb, dp, chunk, a);
  barrier_lgkm();
  if (dir == 0) scan_fix<false>(sb, dp, chunk, a);
  else          scan_fix<true >(sb, dp, chunk, a);
}

// acc2 += h @ M[dir] in D[pos][c] orientation.
DEVINL void combine64(const char* buf, const u16* __restrict__ Mrow, int dir, int e,
                      int lane, int wv, f32x4v (&acc2)[4][2]) {
  const int l15 = lane & 15, kg = lane >> 4;
#pragma unroll
  for (int ks = 0; ks < 2; ++ks) {
    bf16x8 afr[4], bfr[2];
#pragma unroll
    for (int ct = 0; ct < 4; ++ct)
      afr[ct] = *(const bf16x8*)(Mrow + ((size_t)dir * 64 + ct * 16 + l15) * 128 + e * 64 + ks * 32 + kg * 8);
#pragma unroll
    for (int pt = 0; pt < 2; ++pt) {
      const int row = wv * 32 + pt * 16 + l15;
      bfr[pt] = *(const bf16x8*)(buf + row * 128 + ((u32)(ks * 64 + kg * 16) ^ ((u32)((row & 7) << 4))));
    }
#pragma unroll
    for (int ct = 0; ct < 4; ++ct)
#pragma unroll
      for (int pt = 0; pt < 2; ++pt)
        acc2[ct][pt] = __builtin_amdgcn_mfma_f32_16x16x32_bf16(bfr[pt], afr[ct], acc2[ct][pt], 0, 0, 0);
  }
}

// Store combine acc into smem as f32 [64 c][512B swz rows].
DEVINL void acc_to_outs(const f32x4v (&acc2)[4][2], int lane, int wv, char* buf) {
  const int l15 = lane & 15, kg = lane >> 4;
#pragma unroll
  for (int ct = 0; ct < 4; ++ct)
#pragma unroll
    for (int pt = 0; pt < 2; ++pt) {
      const int c = ct * 16 + l15;
      const int pos = wv * 32 + pt * 16 + kg * 4;
      *(f32x4v*)(buf + c * 512 + ((u32)(pos * 4) ^ ((u32)((c & 7) << 4)))) = acc2[ct][pt];
    }
}

// Epilogue: OutS -> partial [64 c][128 pos] bf16 stream (16 KB).
DEVINL void outs_to_global(const char* buf, u16* __restrict__ og, int t) {
#pragma unroll
  for (int j = 0; j < 16; ++j) {
    const int i = t + j * 256;
    const int c = i >> 6, p2 = (i & 63) * 2;
    const f32x2 v = *(const f32x2*)(buf + c * 512 + ((u32)(p2 * 4) ^ ((u32)((c & 7) << 4))));
    *(u32*)(og + c * 128 + p2) = pack2(v.x, v.y);
  }
}

// ---- F prefetch: 32 alpha-fused values per thread into registers ----
DEVINL void load_F(const float* __restrict__ F_in, const float* __restrict__ prior,
                   float alpha, int b, int h, int t, float (&fv)[32]) {
  const int w = t & 127, ch = t >> 7;
  const float pv = prior[(b * 128 + h) * 128 + w];
  const float* Fb = F_in + ((size_t)b * 64 + ch * 32) * 16384 + h * 128 + w;
#pragma unroll
  for (int q = 0; q < 4; ++q)
#pragma unroll
    for (int j = 0; j < 8; ++j)
      fv[q * 8 + j] = fmaf(alpha, pv, Fb[(q * 8 + j) * 16384]);
}

DEVINL void stage_F(char* bufA, int t, const float (&fv)[32]) {
  const int w = t & 127, ch = t >> 7;
  const u32 sw = (u32)((w & 7) << 4);
  char* rowp = bufA + w * 128;
#pragma unroll
  for (int q = 0; q < 4; ++q) {
    uint4 pk;
    pk.x = pack2(fv[q * 8 + 0], fv[q * 8 + 1]); pk.y = pack2(fv[q * 8 + 2], fv[q * 8 + 3]);
    pk.z = pack2(fv[q * 8 + 4], fv[q * 8 + 5]); pk.w = pack2(fv[q * 8 + 6], fv[q * 8 + 7]);
    *(uint4*)(rowp + ((u32)(ch * 64 + q * 16) ^ sw)) = pk;
  }
}

// ---------------- tile A: GEMM + h-scans + combine, with optional next-tile F prefetch ----
template <bool PRE>
DEVINL void tileA(char* bufA, char* bufB, int t, int lane, int wv, int l15, int kg,
                  int tid, const float* __restrict__ F_in, const float* __restrict__ prior,
                  float alpha, const u16* __restrict__ Wi_bf, const float* __restrict__ bi,
                  const float* __restrict__ Bp, const float* __restrict__ A_t,
                  const u16* __restrict__ Mrow, u16* __restrict__ x2, u16* __restrict__ Shp,
                  const float (&fvcur)[32], float (&fvnext)[32], int tidnext) {
  const int e = tid & 1;

  // P1: stage Fmod^T (from registers)
  stage_F(bufA, t, fvcur);
  barrier_lgkm();

  // P2: Fmod B-frags into regs
  bf16x8 bF[2][2];
#pragma unroll
  for (int wj = 0; wj < 2; ++wj)
#pragma unroll
    for (int ks = 0; ks < 2; ++ks) {
      const int row = wv * 32 + wj * 16 + l15;
      bF[wj][ks] = *(const bf16x8*)(bufA + row * 128 + ((u32)(ks * 64 + kg * 16) ^ ((u32)((row & 7) << 4))));
    }
  barrier_lgkm();

  // P3: GEMM D[d][w]; prescale by B_d; Bx -> bufA + bufB
  {
    f32x4v acc[4][2];
#pragma unroll
    for (int dt = 0; dt < 4; ++dt) {
      const f32x4 bv = *(const f32x4*)(bi + e * 64 + dt * 16 + kg * 4);
      const f32x4v bvv = { bv.x, bv.y, bv.z, bv.w };
#pragma unroll
      for (int wj = 0; wj < 2; ++wj) acc[dt][wj] = bvv;
    }
#pragma unroll
    for (int ks = 0; ks < 2; ++ks)
#pragma unroll
      for (int dt = 0; dt < 4; ++dt) {
        const bf16x8 aWi = *(const bf16x8*)(Wi_bf + (e * 64 + dt * 16 + l15) * 64 + ks * 32 + kg * 8);
        acc[dt][0] = __builtin_amdgcn_mfma_f32_16x16x32_bf16(aWi, bF[0][ks], acc[dt][0], 0, 0, 0);
        acc[dt][1] = __builtin_amdgcn_mfma_f32_16x16x32_bf16(aWi, bF[1][ks], acc[dt][1], 0, 0, 0);
      }
#pragma unroll
    for (int dt = 0; dt < 4; ++dt) {
      const f32x4 B4 = *(const f32x4*)(Bp + e * 64 + dt * 16 + kg * 4);
      const f32x4v B4v = { B4.x, B4.y, B4.z, B4.w };
#pragma unroll
      for (int wj = 0; wj < 2; ++wj) {
        const f32x4v sv = acc[dt][wj] * B4v;
        const int w = wv * 32 + wj * 16 + l15;
        const int dl = dt * 16 + kg * 4;
        uint2 pk;
        pk.x = pack2(sv[0], sv[1]);
        pk.y = pack2(sv[2], sv[3]);
        const u32 col = (u32)(dl * 2) ^ ((u32)((w & 7) << 4));
        *(uint2*)(bufA + w * 128 + col) = pk;
        *(uint2*)(bufB + w * 128 + col) = pk;
      }
    }
  }

  // Prefetch next tile's F into registers — drains under P4..P8.
  if (PRE) load_F(F_in, prior, alpha, tidnext >> 8, (tidnext >> 1) & 127, t, fvnext);
  barrier_lgkm();

  // P4: Bx -> global x2 (16 KB stream); stores drain under scans.
  {
    u16* xg = x2 + (size_t)tid * 8192;
#pragma unroll
    for (int j = 0; j < 4; ++j) {
      const int idx = t + j * 256;
      const int row = idx >> 3, q = idx & 7;
      const uint4 v = *(const uint4*)(bufA + row * 128 + ((u32)(q * 16) ^ ((u32)((row & 7) << 4))));
      *(uint4*)(xg + row * 64 + q * 8) = v;
    }
  }
  barrier_lgkm();

  // P5: scans
  run_scans(bufA, bufB, t, e, A_t);
  barrier_lgkm();

  // P6: combine
  f32x4v acc2[4][2];
#pragma unroll
  for (int i = 0; i < 4; ++i)
#pragma unroll
    for (int j = 0; j < 2; ++j) acc2[i][j] = (f32x4v)0.f;
  combine64(bufA, Mrow, 0, e, lane, wv, acc2);
  combine64(bufB, Mrow, 1, e, lane, wv, acc2);
  barrier_lgkm();

  // P7 + P8
  acc_to_outs(acc2, lane, wv, bufA);
  barrier_lgkm();
  outs_to_global(bufA, Shp + (size_t)tid * 8192, t);
}

// ---------------- K_A: persistent 2-tile blocks ----------------
__global__ __launch_bounds__(256, 5) void k_A(
    const float* __restrict__ F_in, const float* __restrict__ prior,
    const u16* __restrict__ Wi_bf, const float* __restrict__ bi,
    const float* __restrict__ Bp, const float* __restrict__ alpha_p,
    const float* __restrict__ A_t, const u16* __restrict__ Mrow,
    u16* __restrict__ x2, u16* __restrict__ Shp) {
  char* bufA = smem;
  char* bufB = smem + 16384;
  const int t = threadIdx.x;
  const int lane = t & 63, wv = t >> 6, l15 = lane & 15, kg = lane >> 4;
  const int bid = blockIdx.x;
  const float alpha = alpha_p[0];

  float fv0[32], fv1[32];
  load_F(F_in, prior, alpha, bid >> 8, (bid >> 1) & 127, t, fv0);
  tileA<true >(bufA, bufB, t, lane, wv, l15, kg, bid, F_in, prior, alpha,
               Wi_bf, bi, Bp, A_t, Mrow, x2, Shp, fv0, fv1, bid + 1024);
  barrier_lgkm();   // OutS reads done before tile1 stage overwrites
  tileA<false>(bufA, bufB, t, lane, wv, l15, kg, bid + 1024, F_in, prior, alpha,
               Wi_bf, bi, Bp, A_t, Mrow, x2, Shp, fv1, fv1, 0);
}

// ---- x2 prefetch for k_B ----
DEVINL void load_X(const u16* __restrict__ x2, int b, int w, int e, int t, uint4 (&xv)[4]) {
#pragma unroll
  for (int j = 0; j < 4; ++j) {
    const int idx = t + j * 256;
    const int hh = idx >> 3, q = idx & 7;
    xv[j] = *(const uint4*)(x2 + ((size_t)((b * 128 + hh) * 2 + e)) * 8192 + w * 64 + q * 8);
  }
}

DEVINL void stage_X(char* bufA, char* bufB, int t, const uint4 (&xv)[4]) {
#pragma unroll
  for (int j = 0; j < 4; ++j) {
    const int idx = t + j * 256;
    const int hh = idx >> 3, q = idx & 7;
    const u32 col = (u32)(q * 16) ^ ((u32)((hh & 7) << 4));
    *(uint4*)(bufA + hh * 128 + col) = xv[j];
    *(uint4*)(bufB + hh * 128 + col) = xv[j];
  }
}

// ---------------- tile B: v-scans + combine, with optional next-tile x prefetch ----
template <bool PRE>
DEVINL void tileB(char* bufA, char* bufB, int t, int lane, int wv,
                  int tid, const u16* __restrict__ x2, const float* __restrict__ A_t,
                  const u16* __restrict__ Mrow, u16* __restrict__ Svp,
                  const uint4 (&xcur)[4], uint4 (&xnext)[4], int tidnext) {
  const int e = tid & 1;
  stage_X(bufA, bufB, t, xcur);
  if (PRE) load_X(x2, tidnext >> 8, (tidnext >> 1) & 127, tidnext & 1, t, xnext);
  barrier_lgkm();

  run_scans(bufA, bufB, t, e, A_t);
  barrier_lgkm();

  f32x4v acc2[4][2];
#pragma unroll
  for (int i = 0; i < 4; ++i)
#pragma unroll
    for (int j = 0; j < 2; ++j) acc2[i][j] = (f32x4v)0.f;
  combine64(bufA, Mrow, 2, e, lane, wv, acc2);
  combine64(bufB, Mrow, 3, e, lane, wv, acc2);
  barrier_lgkm();

  acc_to_outs(acc2, lane, wv, bufA);
  barrier_lgkm();
  outs_to_global(bufA, Svp + (size_t)tid * 8192, t);
}

// ---------------- K_B: persistent 2-tile blocks ----------------
__global__ __launch_bounds__(256, 5) void k_B(
    const u16* __restrict__ x2,
    const float* __restrict__ A_t, const u16* __restrict__ Mrow,
    u16* __restrict__ Svp) {
  char* bufA = smem;
  char* bufB = smem + 16384;
  const int t = threadIdx.x;
  const int lane = t & 63, wv = t >> 6;
  const int bid = blockIdx.x;

  uint4 xv0[4], xv1[4];
  load_X(x2, bid >> 8, (bid >> 1) & 127, bid & 1, t, xv0);
  tileB<true >(bufA, bufB, t, lane, wv, bid, x2, A_t, Mrow, Svp, xv0, xv1, bid + 1024);
  barrier_lgkm();
  tileB<false>(bufA, bufB, t, lane, wv, bid + 1024, x2, A_t, Mrow, Svp, xv1, xv1, 0);
}

// ---------------- F: out = F_mod + gamma*(Sh0+Sh1 + (Sv0+Sv1)^T + beff) ----------------
__global__ __launch_bounds__(256) void k_final(
    const float* __restrict__ F_in, const float* __restrict__ prior,
    const float* __restrict__ alpha_p, const float* __restrict__ gamma_p,
    const float* __restrict__ beff, const u16* __restrict__ Svp,
    const u16* __restrict__ Shp, float* __restrict__ out) {
  u16* Xu = (u16*)smem;
  const int t = threadIdx.x;
  const int bid = blockIdx.x, b = bid >> 6, c = bid & 63;
  const size_t base = (size_t)bid * 16384;   // (b,c) plane of out/F

  // stage Sv = Svp(e0)+Svp(e1), transposed via LDS: Xu[w][h], stride 132
  for (int i = t; i < 2048; i += 256) {
    const int w = i >> 4, q = i & 15;
    const u16* s0 = Svp + ((size_t)((b * 128 + w) * 2)) * 8192 + c * 128 + q * 8;
    const uint4 a4 = *(const uint4*)(s0);
    const uint4 b4 = *(const uint4*)(s0 + 8192);
    const u16* ap = (const u16*)&a4;
    const u16* bp = (const u16*)&b4;
    u32* dst = (u32*)(Xu + w * 132 + q * 8);
#pragma unroll
    for (int k = 0; k < 4; ++k) {
      const float lo = bf2f(ap[k * 2]) + bf2f(bp[k * 2]);
      const float hi = bf2f(ap[k * 2 + 1]) + bf2f(bp[k * 2 + 1]);
      dst[k] = pack2(lo, hi);
    }
  }
  __syncthreads();
  const float alpha = alpha_p[0], gamma = gamma_p[0];
  const float be = beff[c];
  for (int i = t; i < 2048; i += 256) {
    const int hh = i >> 4, w8 = (i & 15) * 8;
    const size_t off = base + hh * 128 + w8;
    const u16* sh0 = Shp + ((size_t)((b * 128 + hh) * 2)) * 8192 + c * 128 + w8;
    const uint4 g0 = *(const uint4*)(sh0);
    const uint4 g1 = *(const uint4*)(sh0 + 8192);
    const u16* p0 = (const u16*)&g0;
    const u16* p1 = (const u16*)&g1;
    const float* Fp = F_in + off;
    float* Op = out + off;
    const float* Pp = prior + (b * 128 + hh) * 128 + w8;
#pragma unroll
    for (int q = 0; q < 8; ++q) {
      const float sv = bf2f(Xu[(w8 + q) * 132 + hh]);
      Op[q] = Fp[q] + alpha * Pp[q] + gamma * (bf2f(p0[q]) + bf2f(p1[q]) + sv + be);
    }
  }
}

extern "C" void kernel_launch(void* const* d_in, const int* in_sizes, int n_in,
                              void* d_out, int out_size, void* d_ws, size_t ws_size,
                              hipStream_t stream) {
  const float* F_in   = (const float*)d_in[0];
  const float* prior  = (const float*)d_in[1];
  const float* Wi     = (const float*)d_in[2];
  const float* bi     = (const float*)d_in[3];
  const float* A_par  = (const float*)d_in[4];
  const float* B_par  = (const float*)d_in[5];
  const float* alpha  = (const float*)d_in[6];
  const float* gamma  = (const float*)d_in[7];
  const float* Wf     = (const float*)d_in[8];
  const float* bf_    = (const float*)d_in[9];
  const float* Wo     = (const float*)d_in[10];
  const float* bo     = (const float*)d_in[11];
  float* out = (float*)d_out;

  char* ws = (char*)d_ws;
  float* A_t   = (float*)ws;                        // 512 B
  float* beff  = (float*)(ws + 512);                // 256 B
  u16*   Mrow  = (u16*)(ws + 1024);                 // 64 KB: [4][64][128] bf16
  u16*   Wi_bf = (u16*)(ws + 66560);                // 16 KB: [128][64] bf16
  u16*   x2    = (u16*)(ws + 82944);                // 33.5 MB: [2048][128 w][64 d] (B-prescaled)
  u16*   Shp   = (u16*)(ws + 82944 + 33554432);     // 33.5 MB: [2048][64 c][128 w]
  u16*   Svp   = (u16*)(ws + 82944 + 67108864);     // 33.5 MB: [2048][64 c][128 h]

  hipFuncSetAttribute((const void*)k_A, hipFuncAttributeMaxDynamicSharedMemorySize, SCAN_LDS);
  hipFuncSetAttribute((const void*)k_B, hipFuncAttributeMaxDynamicSharedMemorySize, SCAN_LDS);

  k_pre  <<<130, 256, 0, stream>>>(Wf, Wo, bf_, bo, A_par, Wi, A_t, beff, Mrow, Wi_bf);
  k_A    <<<1024, 256, SCAN_LDS, stream>>>(F_in, prior, Wi_bf, bi, B_par, alpha, A_t, Mrow, x2, Shp);
  k_B    <<<1024, 256, SCAN_LDS, stream>>>(x2, A_t, Mrow, Svp);
  k_final<<<512, 256, LDS_X, stream>>>(F_in, prior, alpha, gamma, beff, Svp, Shp, out);
}

// Round 19
// 100.535 us; speedup vs baseline: 1.2504x; 1.2504x over previous
//
#include <hip/hip_runtime.h>
#include <hip/hip_bf16.h>

typedef unsigned int u32;
typedef unsigned short u16;
typedef float f32x2 __attribute__((ext_vector_type(2)));
typedef float f32x4 __attribute__((ext_vector_type(4)));
using bf16x8 = __attribute__((ext_vector_type(8))) short;   // MFMA A/B frag (4 VGPRs)
using f32x4v = __attribute__((ext_vector_type(4))) float;   // MFMA C/D frag

#define DEVINL __device__ __forceinline__

// Problem constants: B=8, C=64, D=128, H=128, W=128
// d-split: each k_A/k_B block handles 64 channels (e = 0 or 1).
constexpr int SCAN_LDS = 32768;        // bufA(16K) + bufB(16K)
constexpr int XS = 132;                // k_final transpose staging stride (u16)
constexpr int LDS_X = 128 * XS * 2;    // 33792

DEVINL float bf2f(u16 u) { union { u32 i; float f; } v; v.i = ((u32)u) << 16; return v.f; }
DEVINL float bf2f_lo(u32 u) { union { u32 i; float f; } v; v.i = u << 16; return v.f; }
DEVINL float bf2f_hi(u32 u) { union { u32 i; float f; } v; v.i = u & 0xffff0000u; return v.f; }
DEVINL u16 f2bf(float f) {
  __hip_bfloat16 h = __float2bfloat16(f);
  u16 r; __builtin_memcpy(&r, &h, 2); return r;
}
DEVINL u32 pack2(float a, float b) { return (u32)f2bf(a) | ((u32)f2bf(b) << 16); }

// ---------------- P0: A=tanh(A_param), Mrow[dir][c][d] bf16, beff, Wi_bf ----------------
__global__ __launch_bounds__(256) void k_pre(
    const float* __restrict__ Wf, const float* __restrict__ Wo,
    const float* __restrict__ bf_, const float* __restrict__ bo,
    const float* __restrict__ A_param, const float* __restrict__ Wi,
    float* __restrict__ A_t, float* __restrict__ beff,
    u16* __restrict__ Mrow, u16* __restrict__ Wi_bf) {
  const int wg = blockIdx.x, t = threadIdx.x;
  if (wg < 128) {
    const int idx = wg * 256 + t;          // 0..32767
    const int cout = idx >> 9;             // 0..63
    const int k = idx & 511;               // dir*128 + d
    float s = 0.f;
    for (int d = 0; d < 128; ++d) s = fmaf(Wo[cout * 128 + d], Wf[d * 512 + k], s);
    const int dir = k >> 7, dm = k & 127;
    Mrow[(dir * 64 + cout) * 128 + dm] = f2bf(s);
  } else if (wg == 128) {
    if (t < 128) A_t[t] = tanhf(A_param[t]);
    if (t < 64) {
      float s = bo[t];
      for (int d = 0; d < 128; ++d) s = fmaf(Wo[t * 128 + d], bf_[d], s);
      beff[t] = s;
    }
  } else {
    // Wi[128 d][64 c] f32 -> bf16, same layout
#pragma unroll
    for (int k = 0; k < 32; ++k) {
      const int i = t + k * 256;
      Wi_bf[i] = f2bf(Wi[i]);
    }
  }
}

extern __shared__ char smem[];

// ---- Chunked scan (4 chunks x 32), prescaled input (B*x): h = A*h + xv. ----
template <bool REV>
DEVINL void scan_local(char* buf, int dp, int chunk, f32x2 A2) {
  f32x2 h = { 0.f, 0.f };
  const u32 cb = (u32)(dp * 4);
  const int s = chunk * 32;
  u32 nx[8];
#pragma unroll
  for (int j = 0; j < 8; ++j) {
    const int i = REV ? (127 - (s + j)) : (s + j);
    nx[j] = *(const u32*)(buf + i * 128 + (cb ^ ((u32)((i & 7) << 4))));
  }
  for (int ib = 0; ib < 32; ib += 8) {
    u32 cur[8];
#pragma unroll
    for (int j = 0; j < 8; ++j) cur[j] = nx[j];
    if (ib + 8 < 32) {
#pragma unroll
      for (int j = 0; j < 8; ++j) {
        const int i2 = s + ib + 8 + j;
        const int i = REV ? (127 - i2) : i2;
        nx[j] = *(const u32*)(buf + i * 128 + (cb ^ ((u32)((i & 7) << 4))));
      }
    }
#pragma unroll
    for (int j = 0; j < 8; ++j) {
      const int i2 = s + ib + j;
      const int i = REV ? (127 - i2) : i2;
      const f32x2 xv = { bf2f_lo(cur[j]), bf2f_hi(cur[j]) };
      h = A2 * h + xv;                            // single v_pk_fma (B prescaled)
      *(u32*)(buf + i * 128 + (cb ^ ((u32)((i & 7) << 4)))) = pack2(h.x, h.y);
    }
  }
}

// ---- Carry correction: h_i = l_i + A^{j+1} * C (C folded from chunk-end rows, f32). ----
template <bool REV>
DEVINL void scan_fix(char* buf, int dp, int chunk, f32x2 A2) {
  if (chunk == 0) return;
  f32x2 q = A2;
#pragma unroll
  for (int k = 0; k < 5; ++k) q *= q;            // A^32
  const u32 cb = (u32)(dp * 4);
  f32x2 C = { 0.f, 0.f };
  for (int k = 0; k < chunk; ++k) {
    const int i2 = k * 32 + 31;
    const int i = REV ? (127 - i2) : i2;
    const u32 v = *(const u32*)(buf + i * 128 + (cb ^ ((u32)((i & 7) << 4))));
    const f32x2 xv = { bf2f_lo(v), bf2f_hi(v) };
    C = C * q + xv;
  }
  f32x2 p = A2;
  const int s = chunk * 32;
  u32 nx[8];
#pragma unroll
  for (int j = 0; j < 8; ++j) {
    const int i = REV ? (127 - (s + j)) : (s + j);
    nx[j] = *(const u32*)(buf + i * 128 + (cb ^ ((u32)((i & 7) << 4))));
  }
  for (int ib = 0; ib < 32; ib += 8) {
    u32 cur[8];
#pragma unroll
    for (int j = 0; j < 8; ++j) cur[j] = nx[j];
    if (ib + 8 < 32) {
#pragma unroll
      for (int j = 0; j < 8; ++j) {
        const int i2 = s + ib + 8 + j;
        const int i = REV ? (127 - i2) : i2;
        nx[j] = *(const u32*)(buf + i * 128 + (cb ^ ((u32)((i & 7) << 4))));
      }
    }
#pragma unroll
    for (int j = 0; j < 8; ++j) {
      const int i2 = s + ib + j;
      const int i = REV ? (127 - i2) : i2;
      const f32x2 xv = { bf2f_lo(cur[j]), bf2f_hi(cur[j]) };
      const f32x2 hv = p * C + xv;
      *(u32*)(buf + i * 128 + (cb ^ ((u32)((i & 7) << 4)))) = pack2(hv.x, hv.y);
      p *= A2;
    }
  }
}

// Both scans: dir0 = fwd on bufA, dir1 = rev on bufB; 4 chunks each; 256 threads.
DEVINL void run_scans(char* bufA, char* bufB, int t, int e, const float* __restrict__ A_t) {
  const int dp = t & 31, chunk = (t >> 5) & 3, dir = t >> 7;
  const f32x2 a = *(const f32x2*)(A_t + e * 64 + dp * 2);
  char* sb = dir ? bufB : bufA;
  if (dir == 0) scan_local<false>(sb, dp, chunk, a);
  else          scan_local<true >(sb, dp, chunk, a);
  __syncthreads();
  if (dir == 0) scan_fix<false>(sb, dp, chunk, a);
  else          scan_fix<true >(sb, dp, chunk, a);
}

// acc2 += h @ M[dir] in D[pos][c] orientation (h as A-operand, M as B-operand).
DEVINL void combine64(const char* buf, const u16* __restrict__ Mrow, int dir, int e,
                      int lane, int wv, f32x4v (&acc2)[4][2]) {
  const int l15 = lane & 15, kg = lane >> 4;
#pragma unroll
  for (int ks = 0; ks < 2; ++ks) {
    bf16x8 afr[4], bfr[2];
#pragma unroll
    for (int ct = 0; ct < 4; ++ct)
      afr[ct] = *(const bf16x8*)(Mrow + ((size_t)dir * 64 + ct * 16 + l15) * 128 + e * 64 + ks * 32 + kg * 8);
#pragma unroll
    for (int pt = 0; pt < 2; ++pt) {
      const int row = wv * 32 + pt * 16 + l15;
      bfr[pt] = *(const bf16x8*)(buf + row * 128 + ((u32)(ks * 64 + kg * 16) ^ ((u32)((row & 7) << 4))));
    }
#pragma unroll
    for (int ct = 0; ct < 4; ++ct)
#pragma unroll
      for (int pt = 0; pt < 2; ++pt)
        acc2[ct][pt] = __builtin_amdgcn_mfma_f32_16x16x32_bf16(bfr[pt], afr[ct], acc2[ct][pt], 0, 0, 0);
  }
}

// Store combine acc into smem as f32 [64 c][512B swz rows]; thread's f32x4 is pos-contiguous.
DEVINL void acc_to_outs(const f32x4v (&acc2)[4][2], int lane, int wv, char* buf) {
  const int l15 = lane & 15, kg = lane >> 4;
#pragma unroll
  for (int ct = 0; ct < 4; ++ct)
#pragma unroll
    for (int pt = 0; pt < 2; ++pt) {
      const int c = ct * 16 + l15;
      const int pos = wv * 32 + pt * 16 + kg * 4;
      *(f32x4v*)(buf + c * 512 + ((u32)(pos * 4) ^ ((u32)((c & 7) << 4)))) = acc2[ct][pt];
    }
}

// Epilogue: OutS -> partial [64 c][128 pos] bf16 stream (16 KB).
DEVINL void outs_to_global(const char* buf, u16* __restrict__ og, int t) {
#pragma unroll
  for (int j = 0; j < 16; ++j) {
    const int i = t + j * 256;
    const int c = i >> 6, p2 = (i & 63) * 2;
    const f32x2 v = *(const f32x2*)(buf + c * 512 + ((u32)(p2 * 4) ^ ((u32)((c & 7) << 4))));
    *(u32*)(og + c * 128 + p2) = pack2(v.x, v.y);
  }
}

// ---------------- K_A: x-GEMM (64 d half) + horizontal scans + combine ----------------
// bid = ((b*128)+h)*2+e. Writes x2[bid][w][64] (B-prescaled) and Shp[bid][c][w].
__global__ __launch_bounds__(256, 5) void k_A(
    const float* __restrict__ F_in, const float* __restrict__ prior,
    const u16* __restrict__ Wi_bf, const float* __restrict__ bi,
    const float* __restrict__ Bp, const float* __restrict__ alpha_p,
    const float* __restrict__ A_t, const u16* __restrict__ Mrow,
    u16* __restrict__ x2, u16* __restrict__ Shp) {
  char* bufA = smem;            // 16 KB [128][128B] swz: FT -> Bx -> h_lr
  char* bufB = smem + 16384;    // 16 KB: Bx copy -> h_rl

  const int t = threadIdx.x;
  const int lane = t & 63, wv = t >> 6, l15 = lane & 15, kg = lane >> 4;
  const int bid = blockIdx.x;
  const int b = bid >> 8, h = (bid >> 1) & 127, e = bid & 1;

  // ---- P1: stage Fmod^T bf16 into bufA: row w = 64 c (128B), swz ----
  {
    const int w = t & 127, ch = t >> 7;
    const float alpha = alpha_p[0];
    const float pv = prior[(b * 128 + h) * 128 + w];
    const float* Fb = F_in + ((size_t)b * 64 + ch * 32) * 16384 + h * 128 + w;
    const u32 sw = (u32)((w & 7) << 4);
    char* rowp = bufA + w * 128;
#pragma unroll
    for (int q = 0; q < 4; ++q) {
      float fv[8];
#pragma unroll
      for (int j = 0; j < 8; ++j) fv[j] = fmaf(alpha, pv, Fb[(q * 8 + j) * 16384]);
      uint4 pk;
      pk.x = pack2(fv[0], fv[1]); pk.y = pack2(fv[2], fv[3]);
      pk.z = pack2(fv[4], fv[5]); pk.w = pack2(fv[6], fv[7]);
      *(uint4*)(rowp + ((u32)(ch * 64 + q * 16) ^ sw)) = pk;
    }
  }
  __syncthreads();

  // ---- P2: Fmod B-frags (n=w) into regs before bufA is overwritten ----
  bf16x8 bF[2][2];   // [wj][ks]
#pragma unroll
  for (int wj = 0; wj < 2; ++wj)
#pragma unroll
    for (int ks = 0; ks < 2; ++ks) {
      const int row = wv * 32 + wj * 16 + l15;
      bF[wj][ks] = *(const bf16x8*)(bufA + row * 128 + ((u32)(ks * 64 + kg * 16) ^ ((u32)((row & 7) << 4))));
    }
  __syncthreads();

  // ---- P3: GEMM D[d][w]; prescale by B_d; Bx -> bufA + bufB (8B swizzled) ----
  {
    f32x4v acc[4][2];   // [dt][wj]
#pragma unroll
    for (int dt = 0; dt < 4; ++dt) {
      const f32x4 bv = *(const f32x4*)(bi + e * 64 + dt * 16 + kg * 4);
      const f32x4v bvv = { bv.x, bv.y, bv.z, bv.w };
#pragma unroll
      for (int wj = 0; wj < 2; ++wj) acc[dt][wj] = bvv;
    }
#pragma unroll
    for (int ks = 0; ks < 2; ++ks)
#pragma unroll
      for (int dt = 0; dt < 4; ++dt) {
        const bf16x8 aWi = *(const bf16x8*)(Wi_bf + (e * 64 + dt * 16 + l15) * 64 + ks * 32 + kg * 8);
        acc[dt][0] = __builtin_amdgcn_mfma_f32_16x16x32_bf16(aWi, bF[0][ks], acc[dt][0], 0, 0, 0);
        acc[dt][1] = __builtin_amdgcn_mfma_f32_16x16x32_bf16(aWi, bF[1][ks], acc[dt][1], 0, 0, 0);
      }
#pragma unroll
    for (int dt = 0; dt < 4; ++dt) {
      const f32x4 B4 = *(const f32x4*)(Bp + e * 64 + dt * 16 + kg * 4);
      const f32x4v B4v = { B4.x, B4.y, B4.z, B4.w };
#pragma unroll
      for (int wj = 0; wj < 2; ++wj) {
        const f32x4v sv = acc[dt][wj] * B4v;
        const int w = wv * 32 + wj * 16 + l15;
        const int dl = dt * 16 + kg * 4;          // d_local base
        uint2 pk;
        pk.x = pack2(sv[0], sv[1]);
        pk.y = pack2(sv[2], sv[3]);
        const u32 col = (u32)(dl * 2) ^ ((u32)((w & 7) << 4));
        *(uint2*)(bufA + w * 128 + col) = pk;
        *(uint2*)(bufB + w * 128 + col) = pk;
      }
    }
  }
  __syncthreads();

  // ---- P4: Bx -> global x2 (16 KB coalesced stream from bufA) ----
  {
    u16* xg = x2 + (size_t)bid * 8192;
#pragma unroll
    for (int j = 0; j < 4; ++j) {
      const int idx = t + j * 256;
      const int row = idx >> 3, q = idx & 7;
      const uint4 v = *(const uint4*)(bufA + row * 128 + ((u32)(q * 16) ^ ((u32)((row & 7) << 4))));
      *(uint4*)(xg + row * 64 + q * 8) = v;
    }
  }
  __syncthreads();

  // ---- P5: 4x32 chunked scans (all 256 threads; internal barrier) ----
  run_scans(bufA, bufB, t, e, A_t);
  __syncthreads();

  // ---- P6: combine dir0 (bufA) + dir1 (bufB) ----
  f32x4v acc2[4][2];
#pragma unroll
  for (int i = 0; i < 4; ++i)
#pragma unroll
    for (int j = 0; j < 2; ++j) acc2[i][j] = (f32x4v)0.f;
  combine64(bufA, Mrow, 0, e, lane, wv, acc2);
  combine64(bufB, Mrow, 1, e, lane, wv, acc2);
  __syncthreads();

  // ---- P7: acc -> OutS (32 KB f32 spanning both buffers) ----
  acc_to_outs(acc2, lane, wv, smem);
  __syncthreads();

  // ---- P8: Shp[bid][c][w] (16 KB stream) ----
  outs_to_global(smem, Shp + (size_t)bid * 8192, t);
}

// ---------------- K_B: vertical scans + combine -> Svp[bid][c][h] ----------------
// bid = ((b*128)+w)*2+e.
__global__ __launch_bounds__(256, 5) void k_B(
    const u16* __restrict__ x2,
    const float* __restrict__ A_t, const u16* __restrict__ Mrow,
    u16* __restrict__ Svp) {
  char* bufA = smem;
  char* bufB = smem + 16384;
  const int t = threadIdx.x;
  const int lane = t & 63, wv = t >> 6;
  const int bid = blockIdx.x;
  const int b = bid >> 8, w = (bid >> 1) & 127, e = bid & 1;

  // ---- P1: stage Bx rows (h-major) into both buffers; 128B L3-hot segments ----
#pragma unroll
  for (int j = 0; j < 4; ++j) {
    const int idx = t + j * 256;
    const int hh = idx >> 3, q = idx & 7;
    const uint4 v = *(const uint4*)(x2 + ((size_t)((b * 128 + hh) * 2 + e)) * 8192 + w * 64 + q * 8);
    const u32 col = (u32)(q * 16) ^ ((u32)((hh & 7) << 4));
    *(uint4*)(bufA + hh * 128 + col) = v;
    *(uint4*)(bufB + hh * 128 + col) = v;
  }
  __syncthreads();

  // ---- P2: 4x32 chunked scans ----
  run_scans(bufA, bufB, t, e, A_t);
  __syncthreads();

  // ---- P3: combine dir2 (bufA) + dir3 (bufB) ----
  f32x4v acc2[4][2];
#pragma unroll
  for (int i = 0; i < 4; ++i)
#pragma unroll
    for (int j = 0; j < 2; ++j) acc2[i][j] = (f32x4v)0.f;
  combine64(bufA, Mrow, 2, e, lane, wv, acc2);
  combine64(bufB, Mrow, 3, e, lane, wv, acc2);
  __syncthreads();

  // ---- P4: acc -> OutS ----
  acc_to_outs(acc2, lane, wv, smem);
  __syncthreads();

  // ---- P5: Svp[bid][c][h] (16 KB stream) ----
  outs_to_global(smem, Svp + (size_t)bid * 8192, t);
}

// ---------------- F: out = F_mod + gamma*(Sh0+Sh1 + (Sv0+Sv1)^T + beff) ----------------
__global__ __launch_bounds__(256) void k_final(
    const float* __restrict__ F_in, const float* __restrict__ prior,
    const float* __restrict__ alpha_p, const float* __restrict__ gamma_p,
    const float* __restrict__ beff, const u16* __restrict__ Svp,
    const u16* __restrict__ Shp, float* __restrict__ out) {
  u16* Xu = (u16*)smem;
  const int t = threadIdx.x;
  const int bid = blockIdx.x, b = bid >> 6, c = bid & 63;
  const size_t base = (size_t)bid * 16384;   // (b,c) plane of out/F

  // stage Sv = Svp(e0)+Svp(e1), transposed via LDS: Xu[w][h], stride 132
  for (int i = t; i < 2048; i += 256) {
    const int w = i >> 4, q = i & 15;
    const u16* s0 = Svp + ((size_t)((b * 128 + w) * 2)) * 8192 + c * 128 + q * 8;
    const uint4 a4 = *(const uint4*)(s0);
    const uint4 b4 = *(const uint4*)(s0 + 8192);
    const u16* ap = (const u16*)&a4;
    const u16* bp = (const u16*)&b4;
    u32* dst = (u32*)(Xu + w * 132 + q * 8);
#pragma unroll
    for (int k = 0; k < 4; ++k) {
      const float lo = bf2f(ap[k * 2]) + bf2f(bp[k * 2]);
      const float hi = bf2f(ap[k * 2 + 1]) + bf2f(bp[k * 2 + 1]);
      dst[k] = pack2(lo, hi);
    }
  }
  __syncthreads();
  const float alpha = alpha_p[0], gamma = gamma_p[0];
  const float be = beff[c];
  for (int i = t; i < 2048; i += 256) {
    const int hh = i >> 4, w8 = (i & 15) * 8;
    const size_t off = base + hh * 128 + w8;
    const u16* sh0 = Shp + ((size_t)((b * 128 + hh) * 2)) * 8192 + c * 128 + w8;
    const uint4 g0 = *(const uint4*)(sh0);
    const uint4 g1 = *(const uint4*)(sh0 + 8192);
    const u16* p0 = (const u16*)&g0;
    const u16* p1 = (const u16*)&g1;
    const float* Fp = F_in + off;
    float* Op = out + off;
    const float* Pp = prior + (b * 128 + hh) * 128 + w8;
#pragma unroll
    for (int q = 0; q < 8; ++q) {
      const float sv = bf2f(Xu[(w8 + q) * 132 + hh]);
      Op[q] = Fp[q] + alpha * Pp[q] + gamma * (bf2f(p0[q]) + bf2f(p1[q]) + sv + be);
    }
  }
}

extern "C" void kernel_launch(void* const* d_in, const int* in_sizes, int n_in,
                              void* d_out, int out_size, void* d_ws, size_t ws_size,
                              hipStream_t stream) {
  const float* F_in   = (const float*)d_in[0];
  const float* prior  = (const float*)d_in[1];
  const float* Wi     = (const float*)d_in[2];
  const float* bi     = (const float*)d_in[3];
  const float* A_par  = (const float*)d_in[4];
  const float* B_par  = (const float*)d_in[5];
  const float* alpha  = (const float*)d_in[6];
  const float* gamma  = (const float*)d_in[7];
  const float* Wf     = (const float*)d_in[8];
  const float* bf_    = (const float*)d_in[9];
  const float* Wo     = (const float*)d_in[10];
  const float* bo     = (const float*)d_in[11];
  float* out = (float*)d_out;

  char* ws = (char*)d_ws;
  float* A_t   = (float*)ws;                        // 512 B
  float* beff  = (float*)(ws + 512);                // 256 B
  u16*   Mrow  = (u16*)(ws + 1024);                 // 64 KB: [4][64][128] bf16
  u16*   Wi_bf = (u16*)(ws + 66560);                // 16 KB: [128][64] bf16
  u16*   x2    = (u16*)(ws + 82944);                // 33.5 MB: [2048][128 w][64 d] (B-prescaled)
  u16*   Shp   = (u16*)(ws + 82944 + 33554432);     // 33.5 MB: [2048][64 c][128 w]
  u16*   Svp   = (u16*)(ws + 82944 + 67108864);     // 33.5 MB: [2048][64 c][128 h]

  hipFuncSetAttribute((const void*)k_A, hipFuncAttributeMaxDynamicSharedMemorySize, SCAN_LDS);
  hipFuncSetAttribute((const void*)k_B, hipFuncAttributeMaxDynamicSharedMemorySize, SCAN_LDS);

  k_pre  <<<130, 256, 0, stream>>>(Wf, Wo, bf_, bo, A_par, Wi, A_t, beff, Mrow, Wi_bf);
  k_A    <<<2048, 256, SCAN_LDS, stream>>>(F_in, prior, Wi_bf, bi, B_par, alpha, A_t, Mrow, x2, Shp);
  k_B    <<<2048, 256, SCAN_LDS, stream>>>(x2, A_t, Mrow, Svp);
  k_final<<<512, 256, LDS_X, stream>>>(F_in, prior, alpha, gamma, beff, Svp, Shp, out);
}

// Round 20
// 96.861 us; speedup vs baseline: 1.2979x; 1.0379x over previous
//
#include <hip/hip_runtime.h>
#include <hip/hip_bf16.h>

typedef unsigned int u32;
typedef unsigned short u16;
typedef float f32x2 __attribute__((ext_vector_type(2)));
typedef float f32x4 __attribute__((ext_vector_type(4)));
using bf16x8 = __attribute__((ext_vector_type(8))) short;   // MFMA A/B frag (4 VGPRs)
using f32x4v = __attribute__((ext_vector_type(4))) float;   // MFMA C/D frag

#define DEVINL __device__ __forceinline__

// Problem constants: B=8, C=64, D=128, H=128, W=128
constexpr int LDS_A = 65536;           // k_A: bufA(32K)+bufB(32K), [128][256B] each
constexpr int LDS_B = 32768;           // k_B: bufA(16K)+bufB(16K), [128][128B] each
constexpr int XS = 132;                // k_final transpose staging stride (u16)
constexpr int LDS_X = 128 * XS * 2;    // 33792

DEVINL float bf2f(u16 u) { union { u32 i; float f; } v; v.i = ((u32)u) << 16; return v.f; }
DEVINL float bf2f_lo(u32 u) { union { u32 i; float f; } v; v.i = u << 16; return v.f; }
DEVINL float bf2f_hi(u32 u) { union { u32 i; float f; } v; v.i = u & 0xffff0000u; return v.f; }
DEVINL u16 f2bf(float f) {
  __hip_bfloat16 h = __float2bfloat16(f);
  u16 r; __builtin_memcpy(&r, &h, 2); return r;
}
DEVINL u32 pack2(float a, float b) { return (u32)f2bf(a) | ((u32)f2bf(b) << 16); }

// ---------------- P0: A=tanh(A_param), Mrow[dir][c][d] bf16, beff, Wi_bf ----------------
__global__ __launch_bounds__(256) void k_pre(
    const float* __restrict__ Wf, const float* __restrict__ Wo,
    const float* __restrict__ bf_, const float* __restrict__ bo,
    const float* __restrict__ A_param, const float* __restrict__ Wi,
    float* __restrict__ A_t, float* __restrict__ beff,
    u16* __restrict__ Mrow, u16* __restrict__ Wi_bf) {
  const int wg = blockIdx.x, t = threadIdx.x;
  if (wg < 128) {
    const int idx = wg * 256 + t;          // 0..32767
    const int cout = idx >> 9;             // 0..63
    const int k = idx & 511;               // dir*128 + d
    float s = 0.f;
    for (int d = 0; d < 128; ++d) s = fmaf(Wo[cout * 128 + d], Wf[d * 512 + k], s);
    const int dir = k >> 7, dm = k & 127;
    Mrow[(dir * 64 + cout) * 128 + dm] = f2bf(s);
  } else if (wg == 128) {
    if (t < 128) A_t[t] = tanhf(A_param[t]);
    if (t < 64) {
      float s = bo[t];
      for (int d = 0; d < 128; ++d) s = fmaf(Wo[t * 128 + d], bf_[d], s);
      beff[t] = s;
    }
  } else {
#pragma unroll
    for (int k = 0; k < 32; ++k) {
      const int i = t + k * 256;
      Wi_bf[i] = f2bf(Wi[i]);
    }
  }
}

extern __shared__ char smem[];

// ---- Chunked scan (4 chunks x 32), prescaled input (B*x): h = A*h + xv. ----
template <bool REV, int ROWB>
DEVINL void scan_local(char* buf, int dp, int chunk, f32x2 A2) {
  f32x2 h = { 0.f, 0.f };
  const u32 cb = (u32)(dp * 4);
  const int s = chunk * 32;
  u32 nx[8];
#pragma unroll
  for (int j = 0; j < 8; ++j) {
    const int i = REV ? (127 - (s + j)) : (s + j);
    nx[j] = *(const u32*)(buf + i * ROWB + (cb ^ ((u32)((i & 7) << 4))));
  }
  for (int ib = 0; ib < 32; ib += 8) {
    u32 cur[8];
#pragma unroll
    for (int j = 0; j < 8; ++j) cur[j] = nx[j];
    if (ib + 8 < 32) {
#pragma unroll
      for (int j = 0; j < 8; ++j) {
        const int i2 = s + ib + 8 + j;
        const int i = REV ? (127 - i2) : i2;
        nx[j] = *(const u32*)(buf + i * ROWB + (cb ^ ((u32)((i & 7) << 4))));
      }
    }
#pragma unroll
    for (int j = 0; j < 8; ++j) {
      const int i2 = s + ib + j;
      const int i = REV ? (127 - i2) : i2;
      const f32x2 xv = { bf2f_lo(cur[j]), bf2f_hi(cur[j]) };
      h = A2 * h + xv;
      *(u32*)(buf + i * ROWB + (cb ^ ((u32)((i & 7) << 4)))) = pack2(h.x, h.y);
    }
  }
}

// ---- Carry correction: h_i = l_i + A^{j+1} * C. ----
template <bool REV, int ROWB>
DEVINL void scan_fix(char* buf, int dp, int chunk, f32x2 A2) {
  if (chunk == 0) return;
  f32x2 q = A2;
#pragma unroll
  for (int k = 0; k < 5; ++k) q *= q;            // A^32
  const u32 cb = (u32)(dp * 4);
  f32x2 C = { 0.f, 0.f };
  for (int k = 0; k < chunk; ++k) {
    const int i2 = k * 32 + 31;
    const int i = REV ? (127 - i2) : i2;
    const u32 v = *(const u32*)(buf + i * ROWB + (cb ^ ((u32)((i & 7) << 4))));
    const f32x2 xv = { bf2f_lo(v), bf2f_hi(v) };
    C = C * q + xv;
  }
  f32x2 p = A2;
  const int s = chunk * 32;
  u32 nx[8];
#pragma unroll
  for (int j = 0; j < 8; ++j) {
    const int i = REV ? (127 - (s + j)) : (s + j);
    nx[j] = *(const u32*)(buf + i * ROWB + (cb ^ ((u32)((i & 7) << 4))));
  }
  for (int ib = 0; ib < 32; ib += 8) {
    u32 cur[8];
#pragma unroll
    for (int j = 0; j < 8; ++j) cur[j] = nx[j];
    if (ib + 8 < 32) {
#pragma unroll
      for (int j = 0; j < 8; ++j) {
        const int i2 = s + ib + 8 + j;
        const int i = REV ? (127 - i2) : i2;
        nx[j] = *(const u32*)(buf + i * ROWB + (cb ^ ((u32)((i & 7) << 4))));
      }
    }
#pragma unroll
    for (int j = 0; j < 8; ++j) {
      const int i2 = s + ib + j;
      const int i = REV ? (127 - i2) : i2;
      const f32x2 xv = { bf2f_lo(cur[j]), bf2f_hi(cur[j]) };
      const f32x2 hv = p * C + xv;
      *(u32*)(buf + i * ROWB + (cb ^ ((u32)((i & 7) << 4)))) = pack2(hv.x, hv.y);
      p *= A2;
    }
  }
}

// ---------------- K_A: 512 threads, full-d: GEMM + h-scans + combine ----------------
// bid = b*128+h. Writes x2[bid][w][128d] (B-prescaled, 32 KB stream) and
// Shp[bid][c][w] (FULL sum over d, 16 KB stream).
__global__ __launch_bounds__(512, 4) void k_A(
    const float* __restrict__ F_in, const float* __restrict__ prior,
    const u16* __restrict__ Wi_bf, const float* __restrict__ bi,
    const float* __restrict__ Bp, const float* __restrict__ alpha_p,
    const float* __restrict__ A_t, const u16* __restrict__ Mrow,
    u16* __restrict__ x2, u16* __restrict__ Shp) {
  char* bufA = smem;            // 32 KB [128 w][256B] swz: FT(first 128B/row) -> Bx -> h_lr
  char* bufB = smem + 32768;    // 32 KB: Bx copy -> h_rl

  const int t = threadIdx.x;
  const int lane = t & 63, wv = t >> 6;           // wv 0..7
  const int l15 = lane & 15, kg = lane >> 4;
  const int bid = blockIdx.x, b = bid >> 7, h = bid & 127;
  const int wq = wv & 3, eh = wv >> 2;            // w-quarter, d/c-half

  // ---- P1: stage Fmod^T bf16 into bufA rows (128B used of 256B): 4 threads/row ----
  {
    const int w = t & 127, ch = t >> 7;           // ch 0..3 -> 16 c each
    const float alpha = alpha_p[0];
    const float pv = prior[(b * 128 + h) * 128 + w];
    const float* Fb = F_in + ((size_t)b * 64 + ch * 16) * 16384 + h * 128 + w;
    const u32 sw = (u32)((w & 7) << 4);
    char* rowp = bufA + w * 256;
#pragma unroll
    for (int q = 0; q < 2; ++q) {
      float fv[8];
#pragma unroll
      for (int j = 0; j < 8; ++j) fv[j] = fmaf(alpha, pv, Fb[(q * 8 + j) * 16384]);
      uint4 pk;
      pk.x = pack2(fv[0], fv[1]); pk.y = pack2(fv[2], fv[3]);
      pk.z = pack2(fv[4], fv[5]); pk.w = pack2(fv[6], fv[7]);
      *(uint4*)(rowp + ((u32)(ch * 32 + q * 16) ^ sw)) = pk;
    }
  }
  __syncthreads();

  // ---- P2: Fmod B-frags (n=w, k=c 0..63) into regs ----
  bf16x8 bF[2][2];   // [wj][ks]
#pragma unroll
  for (int wj = 0; wj < 2; ++wj)
#pragma unroll
    for (int ks = 0; ks < 2; ++ks) {
      const int row = wq * 32 + wj * 16 + l15;
      bF[wj][ks] = *(const bf16x8*)(bufA + row * 256 + ((u32)(ks * 64 + kg * 16) ^ ((u32)((row & 7) << 4))));
    }
  __syncthreads();

  // ---- P3: GEMM D[d][w] (d-half eh); prescale by B_d; Bx -> bufA + bufB ----
  {
    f32x4v acc[4][2];   // [dt][wj]
#pragma unroll
    for (int dt = 0; dt < 4; ++dt) {
      const f32x4 bv = *(const f32x4*)(bi + eh * 64 + dt * 16 + kg * 4);
      const f32x4v bvv = { bv.x, bv.y, bv.z, bv.w };
#pragma unroll
      for (int wj = 0; wj < 2; ++wj) acc[dt][wj] = bvv;
    }
#pragma unroll
    for (int ks = 0; ks < 2; ++ks)
#pragma unroll
      for (int dt = 0; dt < 4; ++dt) {
        const bf16x8 aWi = *(const bf16x8*)(Wi_bf + (eh * 64 + dt * 16 + l15) * 64 + ks * 32 + kg * 8);
        acc[dt][0] = __builtin_amdgcn_mfma_f32_16x16x32_bf16(aWi, bF[0][ks], acc[dt][0], 0, 0, 0);
        acc[dt][1] = __builtin_amdgcn_mfma_f32_16x16x32_bf16(aWi, bF[1][ks], acc[dt][1], 0, 0, 0);
      }
#pragma unroll
    for (int dt = 0; dt < 4; ++dt) {
      const f32x4 B4 = *(const f32x4*)(Bp + eh * 64 + dt * 16 + kg * 4);
      const f32x4v B4v = { B4.x, B4.y, B4.z, B4.w };
#pragma unroll
      for (int wj = 0; wj < 2; ++wj) {
        const f32x4v sv = acc[dt][wj] * B4v;
        const int w = wq * 32 + wj * 16 + l15;
        const int dl = eh * 64 + dt * 16 + kg * 4;
        uint2 pk;
        pk.x = pack2(sv[0], sv[1]);
        pk.y = pack2(sv[2], sv[3]);
        const u32 col = (u32)(dl * 2) ^ ((u32)((w & 7) << 4));
        *(uint2*)(bufA + w * 256 + col) = pk;
        *(uint2*)(bufB + w * 256 + col) = pk;
      }
    }
  }
  __syncthreads();

  // ---- P4: Bx -> global x2 (32 KB coalesced stream from bufA) ----
  {
    u16* xg = x2 + (size_t)bid * 16384;
#pragma unroll
    for (int j = 0; j < 4; ++j) {
      const int idx = t + j * 512;
      const int row = idx >> 4, q = idx & 15;
      const uint4 v = *(const uint4*)(bufA + row * 256 + ((u32)(q * 16) ^ ((u32)((row & 7) << 4))));
      *(uint4*)(xg + row * 128 + q * 8) = v;
    }
  }
  __syncthreads();

  // ---- P5: 4x32 chunked scans: 512 threads = 2 dirs x 64 dp x 4 chunks ----
  {
    const int sub = t & 255, dp = sub & 63, chunk = sub >> 6, dir = t >> 8;
    const f32x2 a = *(const f32x2*)(A_t + dp * 2);
    char* sb = dir ? bufB : bufA;
    if (dir == 0) scan_local<false, 256>(sb, dp, chunk, a);
    else          scan_local<true , 256>(sb, dp, chunk, a);
    __syncthreads();
    if (dir == 0) scan_fix<false, 256>(sb, dp, chunk, a);
    else          scan_fix<true , 256>(sb, dp, chunk, a);
  }
  __syncthreads();

  // ---- P6: combine, full K=128: S[c][w] = M_lr@h_lr + M_rl@h_rl ----
  f32x4v acc2[2][2];   // [ct][pt]; c-half = eh, w-quarter = wq
#pragma unroll
  for (int i = 0; i < 2; ++i)
#pragma unroll
    for (int j = 0; j < 2; ++j) acc2[i][j] = (f32x4v)0.f;
#pragma unroll
  for (int dir = 0; dir < 2; ++dir) {
    const char* buf = dir ? bufB : bufA;
#pragma unroll
    for (int ks = 0; ks < 4; ++ks) {
      bf16x8 afr[2], bfr[2];
#pragma unroll
      for (int ct = 0; ct < 2; ++ct)
        afr[ct] = *(const bf16x8*)(Mrow + ((size_t)dir * 64 + eh * 32 + ct * 16 + l15) * 128 + ks * 32 + kg * 8);
#pragma unroll
      for (int pt = 0; pt < 2; ++pt) {
        const int row = wq * 32 + pt * 16 + l15;
        bfr[pt] = *(const bf16x8*)(buf + row * 256 + ((u32)(ks * 64 + kg * 16) ^ ((u32)((row & 7) << 4))));
      }
#pragma unroll
      for (int ct = 0; ct < 2; ++ct)
#pragma unroll
        for (int pt = 0; pt < 2; ++pt)
          acc2[ct][pt] = __builtin_amdgcn_mfma_f32_16x16x32_bf16(bfr[pt], afr[ct], acc2[ct][pt], 0, 0, 0);
    }
  }
  __syncthreads();

  // ---- P7: acc -> OutS f32 [64 c][512B swz] (spans bufA+bufB) ----
#pragma unroll
  for (int ct = 0; ct < 2; ++ct)
#pragma unroll
    for (int pt = 0; pt < 2; ++pt) {
      const int c = eh * 32 + ct * 16 + l15;
      const int pos = wq * 32 + pt * 16 + kg * 4;
      *(f32x4v*)(smem + c * 512 + ((u32)(pos * 4) ^ ((u32)((c & 7) << 4)))) = acc2[ct][pt];
    }
  __syncthreads();

  // ---- P8: Shp[bid][c][w] FULL (16 KB stream) ----
  {
    u16* og = Shp + (size_t)bid * 8192;
#pragma unroll
    for (int j = 0; j < 8; ++j) {
      const int i = t + j * 512;
      const int c = i >> 6, p2 = (i & 63) * 2;
      const f32x2 v = *(const f32x2*)(smem + c * 512 + ((u32)(p2 * 4) ^ ((u32)((c & 7) << 4))));
      *(u32*)(og + c * 128 + p2) = pack2(v.x, v.y);
    }
  }
}

// ---------------- K_B: vertical scans + combine -> Svp[bid][c][h] (e-split halves) ----------------
// bid = ((b*128)+w)*2+e.
__global__ __launch_bounds__(256, 5) void k_B(
    const u16* __restrict__ x2,
    const float* __restrict__ A_t, const u16* __restrict__ Mrow,
    u16* __restrict__ Svp) {
  char* bufA = smem;
  char* bufB = smem + 16384;
  const int t = threadIdx.x;
  const int lane = t & 63, wv = t >> 6, l15 = lane & 15, kg = lane >> 4;
  const int bid = blockIdx.x;
  const int b = bid >> 8, w = (bid >> 1) & 127, e = bid & 1;

  // ---- P1: stage Bx rows (h-major, e-half) into both buffers; 128B L3-hot ----
#pragma unroll
  for (int j = 0; j < 4; ++j) {
    const int idx = t + j * 256;
    const int hh = idx >> 3, q = idx & 7;
    const uint4 v = *(const uint4*)(x2 + ((size_t)(b * 128 + hh) * 128 + w) * 128 + e * 64 + q * 8);
    const u32 col = (u32)(q * 16) ^ ((u32)((hh & 7) << 4));
    *(uint4*)(bufA + hh * 128 + col) = v;
    *(uint4*)(bufB + hh * 128 + col) = v;
  }
  __syncthreads();

  // ---- P2: 4x32 chunked scans: 256 threads = 2 dirs x 32 dp x 4 chunks ----
  {
    const int dp = t & 31, chunk = (t >> 5) & 3, dir = t >> 7;
    const f32x2 a = *(const f32x2*)(A_t + e * 64 + dp * 2);
    char* sb = dir ? bufB : bufA;
    if (dir == 0) scan_local<false, 128>(sb, dp, chunk, a);
    else          scan_local<true , 128>(sb, dp, chunk, a);
    __syncthreads();
    if (dir == 0) scan_fix<false, 128>(sb, dp, chunk, a);
    else          scan_fix<true , 128>(sb, dp, chunk, a);
  }
  __syncthreads();

  // ---- P3: combine dir2 (bufA) + dir3 (bufB), K=64 (e-half) ----
  f32x4v acc2[4][2];
#pragma unroll
  for (int i = 0; i < 4; ++i)
#pragma unroll
    for (int j = 0; j < 2; ++j) acc2[i][j] = (f32x4v)0.f;
#pragma unroll
  for (int dir = 0; dir < 2; ++dir) {
    const char* buf = dir ? bufB : bufA;
#pragma unroll
    for (int ks = 0; ks < 2; ++ks) {
      bf16x8 afr[4], bfr[2];
#pragma unroll
      for (int ct = 0; ct < 4; ++ct)
        afr[ct] = *(const bf16x8*)(Mrow + ((size_t)(dir + 2) * 64 + ct * 16 + l15) * 128 + e * 64 + ks * 32 + kg * 8);
#pragma unroll
      for (int pt = 0; pt < 2; ++pt) {
        const int row = wv * 32 + pt * 16 + l15;
        bfr[pt] = *(const bf16x8*)(buf + row * 128 + ((u32)(ks * 64 + kg * 16) ^ ((u32)((row & 7) << 4))));
      }
#pragma unroll
      for (int ct = 0; ct < 4; ++ct)
#pragma unroll
        for (int pt = 0; pt < 2; ++pt)
          acc2[ct][pt] = __builtin_amdgcn_mfma_f32_16x16x32_bf16(bfr[pt], afr[ct], acc2[ct][pt], 0, 0, 0);
    }
  }
  __syncthreads();

  // ---- P4: acc -> OutS f32 [64 c][512B swz] ----
#pragma unroll
  for (int ct = 0; ct < 4; ++ct)
#pragma unroll
    for (int pt = 0; pt < 2; ++pt) {
      const int c = ct * 16 + l15;
      const int pos = wv * 32 + pt * 16 + kg * 4;
      *(f32x4v*)(smem + c * 512 + ((u32)(pos * 4) ^ ((u32)((c & 7) << 4)))) = acc2[ct][pt];
    }
  __syncthreads();

  // ---- P5: Svp[bid][c][h] (16 KB stream) ----
  {
    u16* og = Svp + (size_t)bid * 8192;
#pragma unroll
    for (int j = 0; j < 16; ++j) {
      const int i = t + j * 256;
      const int c = i >> 6, p2 = (i & 63) * 2;
      const f32x2 v = *(const f32x2*)(smem + c * 512 + ((u32)(p2 * 4) ^ ((u32)((c & 7) << 4))));
      *(u32*)(og + c * 128 + p2) = pack2(v.x, v.y);
    }
  }
}

// ---------------- F: out = F_mod + gamma*(Sh + (Sv0+Sv1)^T + beff) ----------------
__global__ __launch_bounds__(256) void k_final(
    const float* __restrict__ F_in, const float* __restrict__ prior,
    const float* __restrict__ alpha_p, const float* __restrict__ gamma_p,
    const float* __restrict__ beff, const u16* __restrict__ Svp,
    const u16* __restrict__ Shp, float* __restrict__ out) {
  u16* Xu = (u16*)smem;
  const int t = threadIdx.x;
  const int bid = blockIdx.x, b = bid >> 6, c = bid & 63;
  const size_t base = (size_t)bid * 16384;   // (b,c) plane of out/F

  // stage Sv = Svp(e0)+Svp(e1), transposed via LDS: Xu[w][h], stride 132
  for (int i = t; i < 2048; i += 256) {
    const int w = i >> 4, q = i & 15;
    const u16* s0 = Svp + ((size_t)((b * 128 + w) * 2)) * 8192 + c * 128 + q * 8;
    const uint4 a4 = *(const uint4*)(s0);
    const uint4 b4 = *(const uint4*)(s0 + 8192);
    const u16* ap = (const u16*)&a4;
    const u16* bp = (const u16*)&b4;
    u32* dst = (u32*)(Xu + w * 132 + q * 8);
#pragma unroll
    for (int k = 0; k < 4; ++k) {
      const float lo = bf2f(ap[k * 2]) + bf2f(bp[k * 2]);
      const float hi = bf2f(ap[k * 2 + 1]) + bf2f(bp[k * 2 + 1]);
      dst[k] = pack2(lo, hi);
    }
  }
  __syncthreads();
  const float alpha = alpha_p[0], gamma = gamma_p[0];
  const float be = beff[c];
  for (int i = t; i < 2048; i += 256) {
    const int hh = i >> 4, w8 = (i & 15) * 8;
    const size_t off = base + hh * 128 + w8;
    const u16* sh0 = Shp + (size_t)(b * 128 + hh) * 8192 + c * 128 + w8;
    const uint4 g0 = *(const uint4*)(sh0);
    const u16* p0 = (const u16*)&g0;
    const float* Fp = F_in + off;
    float* Op = out + off;
    const float* Pp = prior + (b * 128 + hh) * 128 + w8;
#pragma unroll
    for (int q = 0; q < 8; ++q) {
      const float sv = bf2f(Xu[(w8 + q) * 132 + hh]);
      Op[q] = Fp[q] + alpha * Pp[q] + gamma * (bf2f(p0[q]) + sv + be);
    }
  }
}

extern "C" void kernel_launch(void* const* d_in, const int* in_sizes, int n_in,
                              void* d_out, int out_size, void* d_ws, size_t ws_size,
                              hipStream_t stream) {
  const float* F_in   = (const float*)d_in[0];
  const float* prior  = (const float*)d_in[1];
  const float* Wi     = (const float*)d_in[2];
  const float* bi     = (const float*)d_in[3];
  const float* A_par  = (const float*)d_in[4];
  const float* B_par  = (const float*)d_in[5];
  const float* alpha  = (const float*)d_in[6];
  const float* gamma  = (const float*)d_in[7];
  const float* Wf     = (const float*)d_in[8];
  const float* bf_    = (const float*)d_in[9];
  const float* Wo     = (const float*)d_in[10];
  const float* bo     = (const float*)d_in[11];
  float* out = (float*)d_out;

  char* ws = (char*)d_ws;
  float* A_t   = (float*)ws;                        // 512 B
  float* beff  = (float*)(ws + 512);                // 256 B
  u16*   Mrow  = (u16*)(ws + 1024);                 // 64 KB: [4][64][128] bf16
  u16*   Wi_bf = (u16*)(ws + 66560);                // 16 KB: [128][64] bf16
  u16*   x2    = (u16*)(ws + 82944);                // 33.5 MB: [1024][128 w][128 d] (B-prescaled)
  u16*   Shp   = (u16*)(ws + 82944 + 33554432);     // 16.8 MB: [1024][64 c][128 w] (full)
  u16*   Svp   = (u16*)(ws + 82944 + 67108864);     // 33.5 MB: [2048][64 c][128 h] (e-split)

  hipFuncSetAttribute((const void*)k_A, hipFuncAttributeMaxDynamicSharedMemorySize, LDS_A);
  hipFuncSetAttribute((const void*)k_B, hipFuncAttributeMaxDynamicSharedMemorySize, LDS_B);

  k_pre  <<<130, 256, 0, stream>>>(Wf, Wo, bf_, bo, A_par, Wi, A_t, beff, Mrow, Wi_bf);
  k_A    <<<1024, 512, LDS_A, stream>>>(F_in, prior, Wi_bf, bi, B_par, alpha, A_t, Mrow, x2, Shp);
  k_B    <<<2048, 256, LDS_B, stream>>>(x2, A_t, Mrow, Svp);
  k_final<<<512, 256, LDS_X, stream>>>(F_in, prior, alpha, gamma, beff, Svp, Shp, out);
}

// Round 21
// 94.927 us; speedup vs baseline: 1.3243x; 1.0204x over previous
//
#include <hip/hip_runtime.h>
#include <hip/hip_bf16.h>

typedef unsigned int u32;
typedef unsigned short u16;
typedef float f32x2 __attribute__((ext_vector_type(2)));
typedef float f32x4 __attribute__((ext_vector_type(4)));
using bf16x8 = __attribute__((ext_vector_type(8))) short;   // MFMA A/B frag (4 VGPRs)
using f32x4v = __attribute__((ext_vector_type(4))) float;   // MFMA C/D frag

#define DEVINL __device__ __forceinline__

// Problem constants: B=8, C=64, D=128, H=128, W=128
constexpr int LDS_AB = 65536;          // k_A/k_B: bufA(32K)+bufB(32K), [128][256B] each
constexpr int XS = 132;                // k_final transpose staging stride (u16)
constexpr int LDS_X = 128 * XS * 2;    // 33792

DEVINL float bf2f(u16 u) { union { u32 i; float f; } v; v.i = ((u32)u) << 16; return v.f; }
DEVINL float bf2f_lo(u32 u) { union { u32 i; float f; } v; v.i = u << 16; return v.f; }
DEVINL float bf2f_hi(u32 u) { union { u32 i; float f; } v; v.i = u & 0xffff0000u; return v.f; }
DEVINL u16 f2bf(float f) {
  __hip_bfloat16 h = __float2bfloat16(f);
  u16 r; __builtin_memcpy(&r, &h, 2); return r;
}
DEVINL u32 pack2(float a, float b) { return (u32)f2bf(a) | ((u32)f2bf(b) << 16); }

// ---------------- P0: A=tanh(A_param), Mrow[dir][c][d] bf16, beff, Wi_bf ----------------
__global__ __launch_bounds__(256) void k_pre(
    const float* __restrict__ Wf, const float* __restrict__ Wo,
    const float* __restrict__ bf_, const float* __restrict__ bo,
    const float* __restrict__ A_param, const float* __restrict__ Wi,
    float* __restrict__ A_t, float* __restrict__ beff,
    u16* __restrict__ Mrow, u16* __restrict__ Wi_bf) {
  const int wg = blockIdx.x, t = threadIdx.x;
  if (wg < 128) {
    const int idx = wg * 256 + t;          // 0..32767
    const int cout = idx >> 9;             // 0..63
    const int k = idx & 511;               // dir*128 + d
    float s = 0.f;
    for (int d = 0; d < 128; ++d) s = fmaf(Wo[cout * 128 + d], Wf[d * 512 + k], s);
    const int dir = k >> 7, dm = k & 127;
    Mrow[(dir * 64 + cout) * 128 + dm] = f2bf(s);
  } else if (wg == 128) {
    if (t < 128) A_t[t] = tanhf(A_param[t]);
    if (t < 64) {
      float s = bo[t];
      for (int d = 0; d < 128; ++d) s = fmaf(Wo[t * 128 + d], bf_[d], s);
      beff[t] = s;
    }
  } else {
#pragma unroll
    for (int k = 0; k < 32; ++k) {
      const int i = t + k * 256;
      Wi_bf[i] = f2bf(Wi[i]);
    }
  }
}

extern __shared__ char smem[];

// ---- Chunked scan (4 chunks x 32), prescaled input (B*x): h = A*h + xv. ----
template <bool REV>
DEVINL void scan_local(char* buf, int dp, int chunk, f32x2 A2) {
  f32x2 h = { 0.f, 0.f };
  const u32 cb = (u32)(dp * 4);
  const int s = chunk * 32;
  u32 nx[8];
#pragma unroll
  for (int j = 0; j < 8; ++j) {
    const int i = REV ? (127 - (s + j)) : (s + j);
    nx[j] = *(const u32*)(buf + i * 256 + (cb ^ ((u32)((i & 7) << 4))));
  }
  for (int ib = 0; ib < 32; ib += 8) {
    u32 cur[8];
#pragma unroll
    for (int j = 0; j < 8; ++j) cur[j] = nx[j];
    if (ib + 8 < 32) {
#pragma unroll
      for (int j = 0; j < 8; ++j) {
        const int i2 = s + ib + 8 + j;
        const int i = REV ? (127 - i2) : i2;
        nx[j] = *(const u32*)(buf + i * 256 + (cb ^ ((u32)((i & 7) << 4))));
      }
    }
#pragma unroll
    for (int j = 0; j < 8; ++j) {
      const int i2 = s + ib + j;
      const int i = REV ? (127 - i2) : i2;
      const f32x2 xv = { bf2f_lo(cur[j]), bf2f_hi(cur[j]) };
      h = A2 * h + xv;
      *(u32*)(buf + i * 256 + (cb ^ ((u32)((i & 7) << 4)))) = pack2(h.x, h.y);
    }
  }
}

// ---- Carry correction: h_i = l_i + A^{j+1} * C. ----
template <bool REV>
DEVINL void scan_fix(char* buf, int dp, int chunk, f32x2 A2) {
  if (chunk == 0) return;
  f32x2 q = A2;
#pragma unroll
  for (int k = 0; k < 5; ++k) q *= q;            // A^32
  const u32 cb = (u32)(dp * 4);
  f32x2 C = { 0.f, 0.f };
  for (int k = 0; k < chunk; ++k) {
    const int i2 = k * 32 + 31;
    const int i = REV ? (127 - i2) : i2;
    const u32 v = *(const u32*)(buf + i * 256 + (cb ^ ((u32)((i & 7) << 4))));
    const f32x2 xv = { bf2f_lo(v), bf2f_hi(v) };
    C = C * q + xv;
  }
  f32x2 p = A2;
  const int s = chunk * 32;
  u32 nx[8];
#pragma unroll
  for (int j = 0; j < 8; ++j) {
    const int i = REV ? (127 - (s + j)) : (s + j);
    nx[j] = *(const u32*)(buf + i * 256 + (cb ^ ((u32)((i & 7) << 4))));
  }
  for (int ib = 0; ib < 32; ib += 8) {
    u32 cur[8];
#pragma unroll
    for (int j = 0; j < 8; ++j) cur[j] = nx[j];
    if (ib + 8 < 32) {
#pragma unroll
      for (int j = 0; j < 8; ++j) {
        const int i2 = s + ib + 8 + j;
        const int i = REV ? (127 - i2) : i2;
        nx[j] = *(const u32*)(buf + i * 256 + (cb ^ ((u32)((i & 7) << 4))));
      }
    }
#pragma unroll
    for (int j = 0; j < 8; ++j) {
      const int i2 = s + ib + j;
      const int i = REV ? (127 - i2) : i2;
      const f32x2 xv = { bf2f_lo(cur[j]), bf2f_hi(cur[j]) };
      const f32x2 hv = p * C + xv;
      *(u32*)(buf + i * 256 + (cb ^ ((u32)((i & 7) << 4)))) = pack2(hv.x, hv.y);
      p *= A2;
    }
  }
}

// 512-thread scans: 2 dirs x 64 dp x 4 chunks.
DEVINL void run_scans512(char* bufA, char* bufB, int t, const float* __restrict__ A_t) {
  const int sub = t & 255, dp = sub & 63, chunk = sub >> 6, dir = t >> 8;
  const f32x2 a = *(const f32x2*)(A_t + dp * 2);
  char* sb = dir ? bufB : bufA;
  if (dir == 0) scan_local<false>(sb, dp, chunk, a);
  else          scan_local<true >(sb, dp, chunk, a);
  __syncthreads();
  if (dir == 0) scan_fix<false>(sb, dp, chunk, a);
  else          scan_fix<true >(sb, dp, chunk, a);
}

// Full-K combine for 512-thread blocks: acc2[2][2] over (dir_base, dir_base+1).
DEVINL void combine_full(const char* bufA, const char* bufB, const u16* __restrict__ Mrow,
                         int dir_base, int eh, int wq, int l15, int kg,
                         f32x4v (&acc2)[2][2]) {
#pragma unroll
  for (int dir = 0; dir < 2; ++dir) {
    const char* buf = dir ? bufB : bufA;
#pragma unroll
    for (int ks = 0; ks < 4; ++ks) {
      bf16x8 afr[2], bfr[2];
#pragma unroll
      for (int ct = 0; ct < 2; ++ct)
        afr[ct] = *(const bf16x8*)(Mrow + ((size_t)(dir_base + dir) * 64 + eh * 32 + ct * 16 + l15) * 128 + ks * 32 + kg * 8);
#pragma unroll
      for (int pt = 0; pt < 2; ++pt) {
        const int row = wq * 32 + pt * 16 + l15;
        bfr[pt] = *(const bf16x8*)(buf + row * 256 + ((u32)(ks * 64 + kg * 16) ^ ((u32)((row & 7) << 4))));
      }
#pragma unroll
      for (int ct = 0; ct < 2; ++ct)
#pragma unroll
        for (int pt = 0; pt < 2; ++pt)
          acc2[ct][pt] = __builtin_amdgcn_mfma_f32_16x16x32_bf16(bfr[pt], afr[ct], acc2[ct][pt], 0, 0, 0);
    }
  }
}

// acc -> OutS f32 [64 c][512B swz] (spans bufA+bufB), then stream to og[c][pos].
DEVINL void outs_epilogue512(const f32x4v (&acc2)[2][2], int eh, int wq, int l15, int kg,
                             int t, u16* __restrict__ og) {
#pragma unroll
  for (int ct = 0; ct < 2; ++ct)
#pragma unroll
    for (int pt = 0; pt < 2; ++pt) {
      const int c = eh * 32 + ct * 16 + l15;
      const int pos = wq * 32 + pt * 16 + kg * 4;
      *(f32x4v*)(smem + c * 512 + ((u32)(pos * 4) ^ ((u32)((c & 7) << 4)))) = acc2[ct][pt];
    }
  __syncthreads();
#pragma unroll
  for (int j = 0; j < 8; ++j) {
    const int i = t + j * 512;
    const int c = i >> 6, p2 = (i & 63) * 2;
    const f32x2 v = *(const f32x2*)(smem + c * 512 + ((u32)(p2 * 4) ^ ((u32)((c & 7) << 4))));
    *(u32*)(og + c * 128 + p2) = pack2(v.x, v.y);
  }
}

// ---------------- K_A: 512 threads, full-d: GEMM + h-scans + combine ----------------
// bid = b*128+h. Writes x2[bid][w][128d] (B-prescaled) and Shp[bid][c][w] (full).
__global__ __launch_bounds__(512, 4) void k_A(
    const float* __restrict__ F_in, const float* __restrict__ prior,
    const u16* __restrict__ Wi_bf, const float* __restrict__ bi,
    const float* __restrict__ Bp, const float* __restrict__ alpha_p,
    const float* __restrict__ A_t, const u16* __restrict__ Mrow,
    u16* __restrict__ x2, u16* __restrict__ Shp) {
  char* bufA = smem;            // 32 KB [128 w][256B] swz: FT -> Bx -> h_lr
  char* bufB = smem + 32768;    // 32 KB: Bx copy -> h_rl

  const int t = threadIdx.x;
  const int lane = t & 63, wv = t >> 6;           // wv 0..7
  const int l15 = lane & 15, kg = lane >> 4;
  const int bid = blockIdx.x, b = bid >> 7, h = bid & 127;
  const int wq = wv & 3, eh = wv >> 2;            // w-quarter, d/c-half

  // ---- P1: stage Fmod^T bf16 into bufA rows (first 128B/row): 4 threads/row ----
  {
    const int w = t & 127, ch = t >> 7;           // ch 0..3 -> 16 c each
    const float alpha = alpha_p[0];
    const float pv = prior[(b * 128 + h) * 128 + w];
    const float* Fb = F_in + ((size_t)b * 64 + ch * 16) * 16384 + h * 128 + w;
    const u32 sw = (u32)((w & 7) << 4);
    char* rowp = bufA + w * 256;
#pragma unroll
    for (int q = 0; q < 2; ++q) {
      float fv[8];
#pragma unroll
      for (int j = 0; j < 8; ++j) fv[j] = fmaf(alpha, pv, Fb[(q * 8 + j) * 16384]);
      uint4 pk;
      pk.x = pack2(fv[0], fv[1]); pk.y = pack2(fv[2], fv[3]);
      pk.z = pack2(fv[4], fv[5]); pk.w = pack2(fv[6], fv[7]);
      *(uint4*)(rowp + ((u32)(ch * 32 + q * 16) ^ sw)) = pk;
    }
  }
  __syncthreads();

  // ---- P2: Fmod B-frags (n=w, k=c 0..63) into regs ----
  bf16x8 bF[2][2];   // [wj][ks]
#pragma unroll
  for (int wj = 0; wj < 2; ++wj)
#pragma unroll
    for (int ks = 0; ks < 2; ++ks) {
      const int row = wq * 32 + wj * 16 + l15;
      bF[wj][ks] = *(const bf16x8*)(bufA + row * 256 + ((u32)(ks * 64 + kg * 16) ^ ((u32)((row & 7) << 4))));
    }
  __syncthreads();

  // ---- P3: GEMM D[d][w] (d-half eh); prescale by B_d; Bx -> bufA + bufB ----
  {
    f32x4v acc[4][2];   // [dt][wj]
#pragma unroll
    for (int dt = 0; dt < 4; ++dt) {
      const f32x4 bv = *(const f32x4*)(bi + eh * 64 + dt * 16 + kg * 4);
      const f32x4v bvv = { bv.x, bv.y, bv.z, bv.w };
#pragma unroll
      for (int wj = 0; wj < 2; ++wj) acc[dt][wj] = bvv;
    }
#pragma unroll
    for (int ks = 0; ks < 2; ++ks)
#pragma unroll
      for (int dt = 0; dt < 4; ++dt) {
        const bf16x8 aWi = *(const bf16x8*)(Wi_bf + (eh * 64 + dt * 16 + l15) * 64 + ks * 32 + kg * 8);
        acc[dt][0] = __builtin_amdgcn_mfma_f32_16x16x32_bf16(aWi, bF[0][ks], acc[dt][0], 0, 0, 0);
        acc[dt][1] = __builtin_amdgcn_mfma_f32_16x16x32_bf16(aWi, bF[1][ks], acc[dt][1], 0, 0, 0);
      }
#pragma unroll
    for (int dt = 0; dt < 4; ++dt) {
      const f32x4 B4 = *(const f32x4*)(Bp + eh * 64 + dt * 16 + kg * 4);
      const f32x4v B4v = { B4.x, B4.y, B4.z, B4.w };
#pragma unroll
      for (int wj = 0; wj < 2; ++wj) {
        const f32x4v sv = acc[dt][wj] * B4v;
        const int w = wq * 32 + wj * 16 + l15;
        const int dl = eh * 64 + dt * 16 + kg * 4;
        uint2 pk;
        pk.x = pack2(sv[0], sv[1]);
        pk.y = pack2(sv[2], sv[3]);
        const u32 col = (u32)(dl * 2) ^ ((u32)((w & 7) << 4));
        *(uint2*)(bufA + w * 256 + col) = pk;
        *(uint2*)(bufB + w * 256 + col) = pk;
      }
    }
  }
  __syncthreads();

  // ---- P4: Bx -> global x2 (32 KB coalesced stream) ----
  {
    u16* xg = x2 + (size_t)bid * 16384;
#pragma unroll
    for (int j = 0; j < 4; ++j) {
      const int idx = t + j * 512;
      const int row = idx >> 4, q = idx & 15;
      const uint4 v = *(const uint4*)(bufA + row * 256 + ((u32)(q * 16) ^ ((u32)((row & 7) << 4))));
      *(uint4*)(xg + row * 128 + q * 8) = v;
    }
  }
  __syncthreads();

  // ---- P5: scans ----
  run_scans512(bufA, bufB, t, A_t);
  __syncthreads();

  // ---- P6-P8: combine + epilogue ----
  f32x4v acc2[2][2];
#pragma unroll
  for (int i = 0; i < 2; ++i)
#pragma unroll
    for (int j = 0; j < 2; ++j) acc2[i][j] = (f32x4v)0.f;
  combine_full(bufA, bufB, Mrow, 0, eh, wq, l15, kg, acc2);
  __syncthreads();
  outs_epilogue512(acc2, eh, wq, l15, kg, t, Shp + (size_t)bid * 8192);
}

// ---------------- K_B: 512 threads, full-d: v-scans + combine -> Svp[bid][c][h] (full) ----------------
// bid = b*128+w.
__global__ __launch_bounds__(512, 4) void k_B(
    const u16* __restrict__ x2,
    const float* __restrict__ A_t, const u16* __restrict__ Mrow,
    u16* __restrict__ Svp) {
  char* bufA = smem;            // 32 KB [128 h][256B] swz
  char* bufB = smem + 32768;

  const int t = threadIdx.x;
  const int lane = t & 63, wv = t >> 6;
  const int l15 = lane & 15, kg = lane >> 4;
  const int bid = blockIdx.x, b = bid >> 7, w = bid & 127;
  const int wq = wv & 3, eh = wv >> 2;

  // ---- P1: stage x rows (h-major, full 256B rows) into both buffers ----
#pragma unroll
  for (int j = 0; j < 4; ++j) {
    const int idx = t + j * 512;
    const int hh = idx >> 4, q = idx & 15;
    const uint4 v = *(const uint4*)(x2 + ((size_t)(b * 128 + hh) * 128 + w) * 128 + q * 8);
    const u32 col = (u32)(q * 16) ^ ((u32)((hh & 7) << 4));
    *(uint4*)(bufA + hh * 256 + col) = v;
    *(uint4*)(bufB + hh * 256 + col) = v;
  }
  __syncthreads();

  // ---- P2: scans (tb in bufA, bt in bufB) ----
  run_scans512(bufA, bufB, t, A_t);
  __syncthreads();

  // ---- P3-P5: combine (dirs 2,3) + epilogue ----
  f32x4v acc2[2][2];
#pragma unroll
  for (int i = 0; i < 2; ++i)
#pragma unroll
    for (int j = 0; j < 2; ++j) acc2[i][j] = (f32x4v)0.f;
  combine_full(bufA, bufB, Mrow, 2, eh, wq, l15, kg, acc2);
  __syncthreads();
  outs_epilogue512(acc2, eh, wq, l15, kg, t, Svp + (size_t)bid * 8192);
}

// ---------------- F: out = F_mod + gamma*(Sh + Sv^T + beff) ----------------
__global__ __launch_bounds__(256) void k_final(
    const float* __restrict__ F_in, const float* __restrict__ prior,
    const float* __restrict__ alpha_p, const float* __restrict__ gamma_p,
    const float* __restrict__ beff, const u16* __restrict__ Svp,
    const u16* __restrict__ Shp, float* __restrict__ out) {
  u16* Xu = (u16*)smem;
  const int t = threadIdx.x;
  const int bid = blockIdx.x, b = bid >> 6, c = bid & 63;
  const size_t base = (size_t)bid * 16384;   // (b,c) plane of out/F

  // stage Sv transposed via LDS: Xu[w][h], stride 132
  for (int i = t; i < 2048; i += 256) {
    const int w = i >> 4, q = i & 15;
    const uint4 a4 = *(const uint4*)(Svp + (size_t)(b * 128 + w) * 8192 + c * 128 + q * 8);
    u32* dst = (u32*)(Xu + w * 132 + q * 8);
    dst[0] = a4.x; dst[1] = a4.y; dst[2] = a4.z; dst[3] = a4.w;
  }
  __syncthreads();
  const float alpha = alpha_p[0], gamma = gamma_p[0];
  const float be = beff[c];
  for (int i = t; i < 2048; i += 256) {
    const int hh = i >> 4, w8 = (i & 15) * 8;
    const size_t off = base + hh * 128 + w8;
    const uint4 g0 = *(const uint4*)(Shp + (size_t)(b * 128 + hh) * 8192 + c * 128 + w8);
    const u16* p0 = (const u16*)&g0;
    const float* Fp = F_in + off;
    float* Op = out + off;
    const float* Pp = prior + (b * 128 + hh) * 128 + w8;
#pragma unroll
    for (int q = 0; q < 8; ++q) {
      const float sv = bf2f(Xu[(w8 + q) * 132 + hh]);
      Op[q] = Fp[q] + alpha * Pp[q] + gamma * (bf2f(p0[q]) + sv + be);
    }
  }
}

extern "C" void kernel_launch(void* const* d_in, const int* in_sizes, int n_in,
                              void* d_out, int out_size, void* d_ws, size_t ws_size,
                              hipStream_t stream) {
  const float* F_in   = (const float*)d_in[0];
  const float* prior  = (const float*)d_in[1];
  const float* Wi     = (const float*)d_in[2];
  const float* bi     = (const float*)d_in[3];
  const float* A_par  = (const float*)d_in[4];
  const float* B_par  = (const float*)d_in[5];
  const float* alpha  = (const float*)d_in[6];
  const float* gamma  = (const float*)d_in[7];
  const float* Wf     = (const float*)d_in[8];
  const float* bf_    = (const float*)d_in[9];
  const float* Wo     = (const float*)d_in[10];
  const float* bo     = (const float*)d_in[11];
  float* out = (float*)d_out;

  char* ws = (char*)d_ws;
  float* A_t   = (float*)ws;                        // 512 B
  float* beff  = (float*)(ws + 512);                // 256 B
  u16*   Mrow  = (u16*)(ws + 1024);                 // 64 KB: [4][64][128] bf16
  u16*   Wi_bf = (u16*)(ws + 66560);                // 16 KB: [128][64] bf16
  u16*   x2    = (u16*)(ws + 82944);                // 33.5 MB: [1024][128 w][128 d] (B-prescaled)
  u16*   Shp   = (u16*)(ws + 82944 + 33554432);     // 16.8 MB: [1024][64 c][128 w] (full)
  u16*   Svp   = (u16*)(ws + 82944 + 67108864);     // 16.8 MB: [1024][64 c][128 h] (full)

  hipFuncSetAttribute((const void*)k_A, hipFuncAttributeMaxDynamicSharedMemorySize, LDS_AB);
  hipFuncSetAttribute((const void*)k_B, hipFuncAttributeMaxDynamicSharedMemorySize, LDS_AB);

  k_pre  <<<130, 256, 0, stream>>>(Wf, Wo, bf_, bo, A_par, Wi, A_t, beff, Mrow, Wi_bf);
  k_A    <<<1024, 512, LDS_AB, stream>>>(F_in, prior, Wi_bf, bi, B_par, alpha, A_t, Mrow, x2, Shp);
  k_B    <<<1024, 512, LDS_AB, stream>>>(x2, A_t, Mrow, Svp);
  k_final<<<512, 256, LDS_X, stream>>>(F_in, prior, alpha, gamma, beff, Svp, Shp, out);
}